// Round 19
// baseline (168.349 us; speedup 1.0000x reference)
//
#include <hip/hip_runtime.h>
#include <hip/hip_bf16.h>

// N=100000 nodes, E=1.6M edges (dst-sorted), IN_C=256, HID_C=128, OUT_C=256.
// f32 inputs; GEMMs run as bf16 MFMA with f32 accumulate.
// Pipeline: prep(wprep+hist1+rowptr) -> scanA -> scatter_keys
//           -> gemm1(2 blk/CU; count+scale fused; nt x loads)
//           -> gather (high-TLP, one wave per node)
//           -> gemm23 (64KB LDS; W2h1 issue-early prefetch; nt out stores).

typedef __attribute__((ext_vector_type(8))) short short8;
typedef __attribute__((ext_vector_type(4))) float f32x4;

static __device__ __forceinline__ float bf2f(unsigned int u16) {
    union { unsigned int i; float f; } c; c.i = u16 << 16; return c.f;
}
static __device__ __forceinline__ ushort f2bf(float f) {
    union { float f; unsigned int i; } c; c.f = f;
    unsigned int i = c.i;
    return (ushort)((i + 0x7FFFu + ((i >> 16) & 1u)) >> 16);   // RNE
}

constexpr int NCHUNK   = 256;   // edge chunks for bucket sort
constexpr int NBUK_MAX = 512;   // LDS bound (actual buckets = ceil(N/256))
constexpr int WPREP_BLOCKS = (128 * 256 + 128 * 128 + 256 * 128) / 256;  // 320

// ---------------------------------------------------------------------------
// prep: fused wprep + hist1 + rowptr (all independent).
__global__ __launch_bounds__(256) void prep_kernel(
    const float* __restrict__ Wc, const float* __restrict__ W1,
    const float* __restrict__ W2, ushort* __restrict__ WcT,
    ushort* __restrict__ W1b, ushort* __restrict__ W2b,
    const int* __restrict__ src, int* __restrict__ M,
    const int* __restrict__ dst, int* __restrict__ row_ptr,
    int nE, int N, int nBuk, int chunkSz)
{
    __shared__ int cnt[NBUK_MAX];
    const int bid = blockIdx.x, tid = threadIdx.x;

    if (bid < WPREP_BLOCKS) {
        int i = bid * 256 + tid;
        if (i < 128 * 256) {
            int o = i >> 8, k = i & 255;
            WcT[o * 256 + k] = f2bf(Wc[k * 128 + o]);
        } else if (i < 128 * 256 + 128 * 128) {
            int j = i - 128 * 256;
            W1b[j] = f2bf(W1[j]);
        } else {
            int j = i - 128 * 256 - 128 * 128;
            W2b[j] = f2bf(W2[j]);
        }
        return;
    }
    if (bid < WPREP_BLOCKS + NCHUNK) {
        int c = bid - WPREP_BLOCKS;
        for (int i = tid; i < nBuk; i += 256) cnt[i] = 0;
        __syncthreads();
        int e0 = c * chunkSz, e1 = min(e0 + chunkSz, nE);
        for (int e = e0 + tid; e < e1; e += 256)
            atomicAdd(&cnt[src[e] >> 8], 1);        // LDS atomic
        __syncthreads();
        for (int b = tid; b < nBuk; b += 256)
            M[b * NCHUNK + c] = cnt[b];
        return;
    }
    // rowptr
    int e = (bid - WPREP_BLOCKS - NCHUNK) * 256 + tid;
    if (e >= nE) return;
    int d = dst[e];
    if (e == 0) {
        for (int n = 0; n <= d; ++n) row_ptr[n] = 0;
    } else {
        int p = dst[e - 1];
        for (int n = p + 1; n <= d; ++n) row_ptr[n] = e;
    }
    if (e == nE - 1) {
        for (int n = d + 1; n <= N; ++n) row_ptr[n] = nE;
    }
}

// ---------------------------------------------------------------------------
__global__ __launch_bounds__(256) void scanA_kernel(
    int* __restrict__ M, int* __restrict__ tot)
{
    __shared__ int buf[2][NCHUNK];
    int b = blockIdx.x, tid = threadIdx.x;
    int v = M[b * NCHUNK + tid];
    buf[0][tid] = v;
    __syncthreads();
    int pi = 0;
#pragma unroll
    for (int off = 1; off < NCHUNK; off <<= 1) {
        int t = buf[pi][tid];
        if (tid >= off) t += buf[pi][tid - off];
        buf[pi ^ 1][tid] = t;
        __syncthreads();
        pi ^= 1;
    }
    int incl = buf[pi][tid];
    M[b * NCHUNK + tid] = incl - v;                 // exclusive
    if (tid == NCHUNK - 1) tot[b] = incl;
}

// ---------------------------------------------------------------------------
// Wave-0 exclusive scan of tot[0..nBuk) into bb_l[0..nBuk] (LDS), then barrier.
static __device__ __forceinline__ void scan_bb(
    const int* __restrict__ tot, int* bb_l, int nBuk, int tid)
{
    if (tid < 64) {
        int base = 0;
        for (int i0 = 0; i0 < nBuk; i0 += 64) {
            int i = i0 + tid;
            int v = (i < nBuk) ? tot[i] : 0;
            int orig = v;
#pragma unroll
            for (int off = 1; off < 64; off <<= 1) {
                int u = __shfl_up(v, off, 64);
                if (tid >= off) v += u;
            }
            if (i < nBuk) bb_l[i] = base + v - orig;     // exclusive
            base += __shfl(v, 63, 64);                   // chunk total
        }
        if (tid == 0) bb_l[nBuk] = base;
    }
    __syncthreads();
}

__global__ __launch_bounds__(256) void scatter_keys_kernel(
    const int* __restrict__ src, const int* __restrict__ M,
    const int* __restrict__ tot, int* __restrict__ ss,
    int nE, int nBuk, int chunkSz)
{
    __shared__ int cur[NBUK_MAX];
    __shared__ int bb_l[NBUK_MAX + 1];
    int c = blockIdx.x, tid = threadIdx.x;
    scan_bb(tot, bb_l, nBuk, tid);
    for (int i = tid; i < nBuk; i += 256)
        cur[i] = M[i * NCHUNK + c] + bb_l[i];
    __syncthreads();
    int e0 = c * chunkSz, e1 = min(e0 + chunkSz, nE);
    for (int e = e0 + tid; e < e1; e += 256) {
        int s = src[e];
        int pos = atomicAdd(&cur[s >> 8], 1);       // LDS atomic
        ss[pos] = s;
    }
}

// ---------------------------------------------------------------------------
// GEMM1: h1 = bf16[rsqrt(outdeg) * (x @ W_conv)], 128x128 per block, 512 thr.
// Full W_convT in LDS (64 KB, staged once); A in 8 32-K chunks (8 KB LDS)
// with depth-3 register prefetch (non-temporal x loads) -> 2 blocks/CU.
// Out-degree histogram recomputed from bucket-sorted keys ss; scale in
// epilogue.
__global__ __launch_bounds__(512, 4) void gemm1_kernel(
    const float* __restrict__ A, const ushort* __restrict__ B,
    const int* __restrict__ ss, const int* __restrict__ tot,
    ushort* __restrict__ C, int nRows, int nBuk)
{
    __shared__ ushort Bs[128 * 256];   // 64 KB, full W_convT, swizzled
    __shared__ ushort As[128 * 32];    // 8 KB, one 32-K chunk
    __shared__ int hist[128];
    __shared__ int eRange[2];

    const int tid  = threadIdx.x;
    const int lane = tid & 63;
    const int w    = tid >> 6;
    const int wm   = w >> 1;
    const int wn   = w & 1;
    const int r    = lane & 15;
    const int q    = lane >> 4;
    const int row0 = blockIdx.x * 128;

    // ---- stage full B once: 4096 short8 slots, 8 per thread
#pragma unroll
    for (int s = 0; s < 8; ++s) {
        int idx = s * 512 + tid;
        int col = idx >> 5, kg = idx & 31;
        *(short8*)&Bs[col * 256 + ((kg ^ (col & 7)) * 8)] =
            *(const short8*)&B[(size_t)col * 256 + kg * 8];
    }
    if (tid < 128) hist[tid] = 0;

    // ---- wave 0: edge range of this block's bucket (bk = blockIdx>>1)
    if (w == 0) {
        int bk = blockIdx.x >> 1;
        int partial = 0;
        for (int i = lane; i < bk; i += 64) partial += tot[i];
#pragma unroll
        for (int off = 32; off >= 1; off >>= 1)
            partial += __shfl_xor(partial, off, 64);
        if (lane == 0) {
            eRange[0] = partial;
            eRange[1] = partial + tot[bk];
        }
    }

    // ---- A slot ownership: 512 slots (128 rows x 4 kg), 1 per thread
    const int arow = tid >> 2, akg = tid & 3;
    const int aslot = (akg ^ ((arow >> 1) & 3)) * 8;   // swizzled ushort offset

    f32x4 areg[3][2];   // [buf][half]

#define G1_ISSUE(cc, bb)                                                     \
    {                                                                        \
        int g0 = row0 + arow;                                                \
        areg[bb][0] = (f32x4){0.f, 0.f, 0.f, 0.f};                           \
        areg[bb][1] = (f32x4){0.f, 0.f, 0.f, 0.f};                           \
        if (g0 < nRows) {                                                    \
            const f32x4* p = (const f32x4*)&A[(size_t)g0 * 256 + (cc) * 32   \
                                              + akg * 8];                    \
            areg[bb][0] = __builtin_nontemporal_load(p);                     \
            areg[bb][1] = __builtin_nontemporal_load(p + 1);                 \
        }                                                                    \
    }

    G1_ISSUE(0, 0)
    G1_ISSUE(1, 1)
    G1_ISSUE(2, 2)
    __syncthreads();   // eRange + hist-zero visible

    // ---- degree histogram for rows [row0, row0+128) from sorted keys
    {
        int e0 = eRange[0], e1 = eRange[1];
        for (int e = e0 + tid; e < e1; e += 512) {
            int s = ss[e];
            if ((s >> 7) == blockIdx.x)
                atomicAdd(&hist[s & 127], 1);       // LDS atomic
        }
    }

    f32x4 acc[8];
#pragma unroll
    for (int t = 0; t < 8; ++t) acc[t] = (f32x4){0.f, 0.f, 0.f, 0.f};

#pragma unroll
    for (int c = 0; c < 8; ++c) {
        if (c > 0) __syncthreads();          // prior compute done with As
        const int buf = c % 3;
        // convert + write chunk c into As
        {
            f32x4 v0 = areg[buf][0], v1 = areg[buf][1];
            ushort u[8];
            u[0] = f2bf(v0[0]); u[1] = f2bf(v0[1]); u[2] = f2bf(v0[2]); u[3] = f2bf(v0[3]);
            u[4] = f2bf(v1[0]); u[5] = f2bf(v1[1]); u[6] = f2bf(v1[2]); u[7] = f2bf(v1[3]);
            *(short8*)&As[arow * 32 + aslot] = *(const short8*)u;
        }
        if (c + 3 < 8) G1_ISSUE(c + 3, buf)  // refill consumed buffer
        __syncthreads();
        // compute: one K-step of 32
        {
            int ra0 = wm * 32 + r, ra1 = wm * 32 + 16 + r;
            short8 a0 = *(const short8*)&As[ra0 * 32 + ((q ^ ((ra0 >> 1) & 3)) * 8)];
            short8 a1 = *(const short8*)&As[ra1 * 32 + ((q ^ ((ra1 >> 1) & 3)) * 8)];
            int sB = c * 4 + q;
#pragma unroll
            for (int t = 0; t < 4; ++t) {
                int col = wn * 64 + t * 16 + r;
                short8 b = *(const short8*)&Bs[col * 256 + ((sB ^ (col & 7)) * 8)];
                acc[t]     = __builtin_amdgcn_mfma_f32_16x16x32_bf16(a0, b, acc[t], 0, 0, 0);
                acc[4 + t] = __builtin_amdgcn_mfma_f32_16x16x32_bf16(a1, b, acc[4 + t], 0, 0, 0);
            }
        }
    }
#undef G1_ISSUE

    // epilogue: apply src-side normalization (from fused histogram), bf16 h1
#pragma unroll
    for (int fr = 0; fr < 2; ++fr)
#pragma unroll
        for (int t = 0; t < 4; ++t) {
            int col = wn * 64 + t * 16 + r;
#pragma unroll
            for (int reg = 0; reg < 4; ++reg) {
                int lr = wm * 32 + fr * 16 + q * 4 + reg;
                int g = row0 + lr;
                if (g < nRows) {
                    float sc = rsqrtf((float)max(hist[lr], 1));
                    C[(size_t)g * 128 + col] = f2bf(acc[fr * 4 + t][reg] * sc);
                }
            }
        }
}

// ---------------------------------------------------------------------------
// CSR gather over pre-scaled h1: pure sum, one wave per node (high TLP).
// Main loop: 4 edges in flight per lane (16/node); tail: one predicated
// 3-deep batch (clamped indices, masked accumulate) instead of serial singles.
static __device__ __forceinline__ void acc8(float* a, uint4 u) {
    union { unsigned int i; float f; } c;
    c.i = u.x << 16;          a[0] += c.f;
    c.i = u.x & 0xffff0000u;  a[1] += c.f;
    c.i = u.y << 16;          a[2] += c.f;
    c.i = u.y & 0xffff0000u;  a[3] += c.f;
    c.i = u.z << 16;          a[4] += c.f;
    c.i = u.z & 0xffff0000u;  a[5] += c.f;
    c.i = u.w << 16;          a[6] += c.f;
    c.i = u.w & 0xffff0000u;  a[7] += c.f;
}

__global__ __launch_bounds__(256) void gather_kernel(
    const ushort* __restrict__ h1, const int* __restrict__ src,
    const int* __restrict__ rp, const float* __restrict__ b_conv,
    ushort* __restrict__ h2, int N)
{
    int n = (blockIdx.x * 256 + threadIdx.x) >> 6;
    int lane = threadIdx.x & 63;
    if (n >= N) return;
    const int g = lane >> 4;
    const int c = lane & 15;
    int e0 = rp[n], e1 = rp[n + 1];

    float a[8];
#pragma unroll
    for (int j = 0; j < 8; ++j) a[j] = 0.f;

    int e = e0 + g;
    for (; e + 12 < e1; e += 16) {         // 4 edges in flight per lane
        int s0 = src[e], s1 = src[e + 4], s2 = src[e + 8], s3 = src[e + 12];
        uint4 u0 = *(const uint4*)&h1[((size_t)(unsigned)s0 << 7) + c * 8];
        uint4 u1 = *(const uint4*)&h1[((size_t)(unsigned)s1 << 7) + c * 8];
        uint4 u2 = *(const uint4*)&h1[((size_t)(unsigned)s2 << 7) + c * 8];
        uint4 u3 = *(const uint4*)&h1[((size_t)(unsigned)s3 << 7) + c * 8];
        acc8(a, u0); acc8(a, u1); acc8(a, u2); acc8(a, u3);
    }
    if (e < e1) {                          // predicated 3-deep tail
        int sA = src[e];
        int sB = (e + 4 < e1) ? src[e + 4] : sA;
        int sC = (e + 8 < e1) ? src[e + 8] : sA;
        uint4 uA = *(const uint4*)&h1[((size_t)(unsigned)sA << 7) + c * 8];
        uint4 uB = *(const uint4*)&h1[((size_t)(unsigned)sB << 7) + c * 8];
        uint4 uC = *(const uint4*)&h1[((size_t)(unsigned)sC << 7) + c * 8];
        acc8(a, uA);
        if (e + 4 < e1) acc8(a, uB);
        if (e + 8 < e1) acc8(a, uC);
    }

#pragma unroll
    for (int j = 0; j < 8; ++j) {
        a[j] += __shfl_xor(a[j], 16, 64);
        a[j] += __shfl_xor(a[j], 32, 64);
    }

    if (g == 0) {
        float sc = rsqrtf((float)max(e1 - e0, 1));
        ushort o[8];
#pragma unroll
        for (int j = 0; j < 8; ++j)
            o[j] = f2bf(fmaxf(fmaf(a[j], sc, b_conv[c * 8 + j]), 0.f));
        *(short8*)&h2[((size_t)(unsigned)n << 7) + c * 8] = *(const short8*)o;
    }
}

// ---------------------------------------------------------------------------
// GEMM2+GEMM3: 128 rows per block, 512 threads, 64 KB LDS total.
// AsTs (32 KB) holds the h2 tile, then T. Ws (32 KB) is a weight window:
// W1 for stage1, then W2 in two 128-col halves for stage2. W2 half-1 is
// issue-early prefetched into registers during half-0's MFMA phase, then
// ds_written after the barrier (async-STAGE split). nt out stores.
__global__ __launch_bounds__(512) void gemm23_kernel(
    const ushort* __restrict__ A, const ushort* __restrict__ W1b,
    const ushort* __restrict__ W2b, const float* __restrict__ b1,
    const float* __restrict__ b2, float* __restrict__ out, int nRows)
{
    __shared__ ushort AsTs[128 * 128];  // 32 KB: h2 tile, then T tile
    __shared__ ushort Ws[128 * 128];    // 32 KB: W1, then W2 half-windows

    const int tid  = threadIdx.x;
    const int lane = tid & 63;
    const int w    = tid >> 6;
    const int wm   = w >> 1;
    const int wn   = w & 1;
    const int r    = lane & 15;
    const int q    = lane >> 4;
    const int row0 = blockIdx.x * 128;

    // ---- stage h2 tile (guarded) + W1, swizzled
#pragma unroll
    for (int s = 0; s < 4; ++s) {
        int idx = s * 512 + tid;
        int row = idx >> 4, kg = idx & 15;
        int g = row0 + row;
        short8 v = (short8){0, 0, 0, 0, 0, 0, 0, 0};
        if (g < nRows) v = *(const short8*)&A[(size_t)g * 128 + kg * 8];
        *(short8*)&AsTs[row * 128 + ((kg ^ (row & 7)) * 8)] = v;
    }
#pragma unroll
    for (int s = 0; s < 4; ++s) {
        int idx = s * 512 + tid;
        int col = idx >> 4, kg = idx & 15;
        *(short8*)&Ws[col * 128 + ((kg ^ (col & 7)) * 8)] =
            *(const short8*)&W1b[(size_t)col * 128 + kg * 8];
    }
    __syncthreads();

    // ---- stage1: acc1 = h2 @ W1^T  (K=128)
    f32x4 acc1[8];
#pragma unroll
    for (int t = 0; t < 8; ++t) acc1[t] = (f32x4){0.f, 0.f, 0.f, 0.f};
#pragma unroll
    for (int ks = 0; ks < 4; ++ks) {
        int sA = ks * 4 + q;
        int ra0 = wm * 32 + r, ra1 = wm * 32 + 16 + r;
        short8 a0 = *(const short8*)&AsTs[ra0 * 128 + ((sA ^ (ra0 & 7)) * 8)];
        short8 a1 = *(const short8*)&AsTs[ra1 * 128 + ((sA ^ (ra1 & 7)) * 8)];
#pragma unroll
        for (int t = 0; t < 4; ++t) {
            int col = wn * 64 + t * 16 + r;
            short8 b = *(const short8*)&Ws[col * 128 + ((sA ^ (col & 7)) * 8)];
            acc1[t]     = __builtin_amdgcn_mfma_f32_16x16x32_bf16(a0, b, acc1[t], 0, 0, 0);
            acc1[4 + t] = __builtin_amdgcn_mfma_f32_16x16x32_bf16(a1, b, acc1[4 + t], 0, 0, 0);
        }
    }
    __syncthreads();   // AsTs + Ws reads done -> safe to overwrite both

    // ---- T = relu(acc1 + b1) -> AsTs; stage W2 half0 -> Ws;
    //      ISSUE W2 half1 global loads into registers (fly under half0 MFMA)
#pragma unroll
    for (int fr = 0; fr < 2; ++fr)
#pragma unroll
        for (int t = 0; t < 4; ++t) {
            int col = wn * 64 + t * 16 + r;
            float bo = b1[col];
#pragma unroll
            for (int reg = 0; reg < 4; ++reg) {
                int row = wm * 32 + fr * 16 + q * 4 + reg;
                float v = fmaxf(acc1[fr * 4 + t][reg] + bo, 0.f);
                AsTs[row * 128 + (((col >> 3) ^ (row & 7)) * 8) + (col & 7)] = f2bf(v);
            }
        }
#pragma unroll
    for (int s = 0; s < 4; ++s) {
        int idx = s * 512 + tid;
        int col = idx >> 4, kg = idx & 15;
        *(short8*)&Ws[col * 128 + ((kg ^ (col & 7)) * 8)] =
            *(const short8*)&W2b[(size_t)col * 128 + kg * 8];
    }
    short8 w2h1[4];
#pragma unroll
    for (int s = 0; s < 4; ++s) {
        int idx = s * 512 + tid;
        int col = idx >> 4, kg = idx & 15;
        w2h1[s] = *(const short8*)&W2b[(size_t)(128 + col) * 128 + kg * 8];
    }
    __syncthreads();

    // ---- stage2 half 0: cols 0..127 of out
    f32x4 acc2[16];
#pragma unroll
    for (int t = 0; t < 16; ++t) acc2[t] = (f32x4){0.f, 0.f, 0.f, 0.f};
#pragma unroll
    for (int ks = 0; ks < 4; ++ks) {
        int sA = ks * 4 + q;
        int ra0 = wm * 32 + r, ra1 = wm * 32 + 16 + r;
        short8 a0 = *(const short8*)&AsTs[ra0 * 128 + ((sA ^ (ra0 & 7)) * 8)];
        short8 a1 = *(const short8*)&AsTs[ra1 * 128 + ((sA ^ (ra1 & 7)) * 8)];
#pragma unroll
        for (int t = 0; t < 4; ++t) {
            int col = wn * 64 + t * 16 + r;
            short8 b = *(const short8*)&Ws[col * 128 + ((sA ^ (col & 7)) * 8)];
            acc2[t]     = __builtin_amdgcn_mfma_f32_16x16x32_bf16(a0, b, acc2[t], 0, 0, 0);
            acc2[4 + t] = __builtin_amdgcn_mfma_f32_16x16x32_bf16(a1, b, acc2[4 + t], 0, 0, 0);
        }
    }
    __syncthreads();   // Ws reads done

    // ---- write prefetched W2 half1 into Ws (loads already landed)
#pragma unroll
    for (int s = 0; s < 4; ++s) {
        int idx = s * 512 + tid;
        int col = idx >> 4, kg = idx & 15;
        *(short8*)&Ws[col * 128 + ((kg ^ (col & 7)) * 8)] = w2h1[s];
    }
    __syncthreads();

    // ---- stage2 half 1: cols 128..255 of out
#pragma unroll
    for (int ks = 0; ks < 4; ++ks) {
        int sA = ks * 4 + q;
        int ra0 = wm * 32 + r, ra1 = wm * 32 + 16 + r;
        short8 a0 = *(const short8*)&AsTs[ra0 * 128 + ((sA ^ (ra0 & 7)) * 8)];
        short8 a1 = *(const short8*)&AsTs[ra1 * 128 + ((sA ^ (ra1 & 7)) * 8)];
#pragma unroll
        for (int t = 0; t < 4; ++t) {
            int col = wn * 64 + t * 16 + r;
            short8 b = *(const short8*)&Ws[col * 128 + ((sA ^ (col & 7)) * 8)];
            acc2[8 + t]  = __builtin_amdgcn_mfma_f32_16x16x32_bf16(a0, b, acc2[8 + t], 0, 0, 0);
            acc2[12 + t] = __builtin_amdgcn_mfma_f32_16x16x32_bf16(a1, b, acc2[12 + t], 0, 0, 0);
        }
    }

    // ---- epilogue: f32 out + b2 (both halves), non-temporal stores
#pragma unroll
    for (int h = 0; h < 2; ++h)
#pragma unroll
        for (int fr = 0; fr < 2; ++fr)
#pragma unroll
            for (int t = 0; t < 4; ++t) {
                int col = h * 128 + wn * 64 + t * 16 + r;
                float bo = b2[col];
#pragma unroll
                for (int reg = 0; reg < 4; ++reg) {
                    int g = row0 + wm * 32 + fr * 16 + q * 4 + reg;
                    if (g < nRows)
                        __builtin_nontemporal_store(
                            acc2[h * 8 + fr * 4 + t][reg] + bo,
                            &out[(size_t)g * 256 + col]);
                }
            }
}

// ---------------------------------------------------------------------------
extern "C" void kernel_launch(void* const* d_in, const int* in_sizes, int n_in,
                              void* d_out, int out_size, void* d_ws, size_t ws_size,
                              hipStream_t stream)
{
    const float* x      = (const float*)d_in[0];
    const int*   src    = (const int*)d_in[1];
    const int*   dst    = (const int*)d_in[2];
    const float* W_conv = (const float*)d_in[3];
    const float* b_conv = (const float*)d_in[4];
    const float* W1     = (const float*)d_in[5];
    const float* b1     = (const float*)d_in[6];
    const float* W2     = (const float*)d_in[7];
    const float* b2     = (const float*)d_in[8];
    float* out = (float*)d_out;

    const int N  = in_sizes[0] / 256;   // 100000
    const int nE = in_sizes[1];         // 1600000

    const int nBuk    = (N + 255) >> 8;                 // 391
    const int chunkSz = (nE + NCHUNK - 1) / NCHUNK;     // 6250

    // ws layout (ushort units for bf16 region, then ints):
    // h1 [N*128] | h2 [N*128] | WcT [128*256] | W1b [128*128] | W2b [256*128]
    // | rp [N+1] | tot [nBuk] | M [nBuk*NCHUNK] | ss [nE]
    ushort* h1  = (ushort*)d_ws;
    ushort* h2  = h1 + (size_t)N * 128;
    ushort* WcT = h2 + (size_t)N * 128;
    ushort* W1b = WcT + 128 * 256;
    ushort* W2b = W1b + 128 * 128;
    int* rp     = (int*)(W2b + 256 * 128);
    int* tot    = rp + (N + 1);
    int* M      = tot + nBuk;
    int* ss     = M + nBuk * NCHUNK;

    // ---- fused prep: weight convert + bucket hist + rowptr
    const int rowptrBlocks = (nE + 255) / 256;
    prep_kernel<<<WPREP_BLOCKS + NCHUNK + rowptrBlocks, 256, 0, stream>>>(
        W_conv, W1, W2, WcT, W1b, W2b, src, M, dst, rp, nE, N, nBuk, chunkSz);

    // ---- atomic-free bucket sort of src keys ----
    scanA_kernel<<<nBuk, 256, 0, stream>>>(M, tot);
    scatter_keys_kernel<<<NCHUNK, 256, 0, stream>>>(src, M, tot, ss, nE, nBuk, chunkSz);

    const int nBlocks128 = (N + 127) / 128;   // 782
    // h1 = bf16[rsqrt(outdeg) * (x @ W_conv)]  (count fused from ss)
    gemm1_kernel<<<nBlocks128, 512, 0, stream>>>(x, WcT, ss, tot, h1, N, nBuk);

    // h2 = bf16[relu(csr_sum(h1) * rsqrt(indeg) + b_conv)]  (high-TLP)
    gather_kernel<<<(N * 64 + 255) / 256, 256, 0, stream>>>(
        h1, src, rp, b_conv, h2, N);

    // out = relu(h2 @ W1^T + b1) @ W2^T + b2
    gemm23_kernel<<<nBlocks128, 512, 0, stream>>>(h2, W1b, W2b, b1, b2, out, N);
}

// Round 20
// 160.628 us; speedup vs baseline: 1.0481x; 1.0481x over previous
//
#include <hip/hip_runtime.h>
#include <hip/hip_bf16.h>

// N=100000 nodes, E=1.6M edges (dst-sorted), IN_C=256, HID_C=128, OUT_C=256.
// f32 inputs; GEMMs run as bf16 MFMA with f32 accumulate.
// Pipeline: prep(wprep+hist1+rowptr) -> scanA -> scatter_keys
//           -> gemm1(2 blk/CU; count+scale fused) -> gather (high-TLP,
//           one wave per node) -> gemm23 (64KB LDS; nt out stores).
// This is the session-best configuration (R17, 160.9 us).

typedef __attribute__((ext_vector_type(8))) short short8;
typedef __attribute__((ext_vector_type(4))) float f32x4;

static __device__ __forceinline__ float bf2f(unsigned int u16) {
    union { unsigned int i; float f; } c; c.i = u16 << 16; return c.f;
}
static __device__ __forceinline__ ushort f2bf(float f) {
    union { float f; unsigned int i; } c; c.f = f;
    unsigned int i = c.i;
    return (ushort)((i + 0x7FFFu + ((i >> 16) & 1u)) >> 16);   // RNE
}

constexpr int NCHUNK   = 256;   // edge chunks for bucket sort
constexpr int NBUK_MAX = 512;   // LDS bound (actual buckets = ceil(N/256))
constexpr int WPREP_BLOCKS = (128 * 256 + 128 * 128 + 256 * 128) / 256;  // 320

// ---------------------------------------------------------------------------
// prep: fused wprep + hist1 + rowptr (all independent).
__global__ __launch_bounds__(256) void prep_kernel(
    const float* __restrict__ Wc, const float* __restrict__ W1,
    const float* __restrict__ W2, ushort* __restrict__ WcT,
    ushort* __restrict__ W1b, ushort* __restrict__ W2b,
    const int* __restrict__ src, int* __restrict__ M,
    const int* __restrict__ dst, int* __restrict__ row_ptr,
    int nE, int N, int nBuk, int chunkSz)
{
    __shared__ int cnt[NBUK_MAX];
    const int bid = blockIdx.x, tid = threadIdx.x;

    if (bid < WPREP_BLOCKS) {
        int i = bid * 256 + tid;
        if (i < 128 * 256) {
            int o = i >> 8, k = i & 255;
            WcT[o * 256 + k] = f2bf(Wc[k * 128 + o]);
        } else if (i < 128 * 256 + 128 * 128) {
            int j = i - 128 * 256;
            W1b[j] = f2bf(W1[j]);
        } else {
            int j = i - 128 * 256 - 128 * 128;
            W2b[j] = f2bf(W2[j]);
        }
        return;
    }
    if (bid < WPREP_BLOCKS + NCHUNK) {
        int c = bid - WPREP_BLOCKS;
        for (int i = tid; i < nBuk; i += 256) cnt[i] = 0;
        __syncthreads();
        int e0 = c * chunkSz, e1 = min(e0 + chunkSz, nE);
        for (int e = e0 + tid; e < e1; e += 256)
            atomicAdd(&cnt[src[e] >> 8], 1);        // LDS atomic
        __syncthreads();
        for (int b = tid; b < nBuk; b += 256)
            M[b * NCHUNK + c] = cnt[b];
        return;
    }
    // rowptr
    int e = (bid - WPREP_BLOCKS - NCHUNK) * 256 + tid;
    if (e >= nE) return;
    int d = dst[e];
    if (e == 0) {
        for (int n = 0; n <= d; ++n) row_ptr[n] = 0;
    } else {
        int p = dst[e - 1];
        for (int n = p + 1; n <= d; ++n) row_ptr[n] = e;
    }
    if (e == nE - 1) {
        for (int n = d + 1; n <= N; ++n) row_ptr[n] = nE;
    }
}

// ---------------------------------------------------------------------------
__global__ __launch_bounds__(256) void scanA_kernel(
    int* __restrict__ M, int* __restrict__ tot)
{
    __shared__ int buf[2][NCHUNK];
    int b = blockIdx.x, tid = threadIdx.x;
    int v = M[b * NCHUNK + tid];
    buf[0][tid] = v;
    __syncthreads();
    int pi = 0;
#pragma unroll
    for (int off = 1; off < NCHUNK; off <<= 1) {
        int t = buf[pi][tid];
        if (tid >= off) t += buf[pi][tid - off];
        buf[pi ^ 1][tid] = t;
        __syncthreads();
        pi ^= 1;
    }
    int incl = buf[pi][tid];
    M[b * NCHUNK + tid] = incl - v;                 // exclusive
    if (tid == NCHUNK - 1) tot[b] = incl;
}

// ---------------------------------------------------------------------------
// Wave-0 exclusive scan of tot[0..nBuk) into bb_l[0..nBuk] (LDS), then barrier.
static __device__ __forceinline__ void scan_bb(
    const int* __restrict__ tot, int* bb_l, int nBuk, int tid)
{
    if (tid < 64) {
        int base = 0;
        for (int i0 = 0; i0 < nBuk; i0 += 64) {
            int i = i0 + tid;
            int v = (i < nBuk) ? tot[i] : 0;
            int orig = v;
#pragma unroll
            for (int off = 1; off < 64; off <<= 1) {
                int u = __shfl_up(v, off, 64);
                if (tid >= off) v += u;
            }
            if (i < nBuk) bb_l[i] = base + v - orig;     // exclusive
            base += __shfl(v, 63, 64);                   // chunk total
        }
        if (tid == 0) bb_l[nBuk] = base;
    }
    __syncthreads();
}

__global__ __launch_bounds__(256) void scatter_keys_kernel(
    const int* __restrict__ src, const int* __restrict__ M,
    const int* __restrict__ tot, int* __restrict__ ss,
    int nE, int nBuk, int chunkSz)
{
    __shared__ int cur[NBUK_MAX];
    __shared__ int bb_l[NBUK_MAX + 1];
    int c = blockIdx.x, tid = threadIdx.x;
    scan_bb(tot, bb_l, nBuk, tid);
    for (int i = tid; i < nBuk; i += 256)
        cur[i] = M[i * NCHUNK + c] + bb_l[i];
    __syncthreads();
    int e0 = c * chunkSz, e1 = min(e0 + chunkSz, nE);
    for (int e = e0 + tid; e < e1; e += 256) {
        int s = src[e];
        int pos = atomicAdd(&cur[s >> 8], 1);       // LDS atomic
        ss[pos] = s;
    }
}

// ---------------------------------------------------------------------------
// GEMM1: h1 = bf16[rsqrt(outdeg) * (x @ W_conv)], 128x128 per block, 512 thr.
// Full W_convT in LDS (64 KB, staged once); A in 8 32-K chunks (8 KB LDS)
// with depth-3 register prefetch -> ~74 KB LDS, 2 blocks/CU.
// Out-degree histogram recomputed from bucket-sorted keys ss; scale in
// epilogue.
__global__ __launch_bounds__(512, 4) void gemm1_kernel(
    const float* __restrict__ A, const ushort* __restrict__ B,
    const int* __restrict__ ss, const int* __restrict__ tot,
    ushort* __restrict__ C, int nRows, int nBuk)
{
    __shared__ ushort Bs[128 * 256];   // 64 KB, full W_convT, swizzled
    __shared__ ushort As[128 * 32];    // 8 KB, one 32-K chunk
    __shared__ int hist[128];
    __shared__ int eRange[2];

    const int tid  = threadIdx.x;
    const int lane = tid & 63;
    const int w    = tid >> 6;
    const int wm   = w >> 1;
    const int wn   = w & 1;
    const int r    = lane & 15;
    const int q    = lane >> 4;
    const int row0 = blockIdx.x * 128;

    // ---- stage full B once: 4096 short8 slots, 8 per thread
#pragma unroll
    for (int s = 0; s < 8; ++s) {
        int idx = s * 512 + tid;
        int col = idx >> 5, kg = idx & 31;
        *(short8*)&Bs[col * 256 + ((kg ^ (col & 7)) * 8)] =
            *(const short8*)&B[(size_t)col * 256 + kg * 8];
    }
    if (tid < 128) hist[tid] = 0;

    // ---- wave 0: edge range of this block's bucket (bk = blockIdx>>1)
    if (w == 0) {
        int bk = blockIdx.x >> 1;
        int partial = 0;
        for (int i = lane; i < bk; i += 64) partial += tot[i];
#pragma unroll
        for (int off = 32; off >= 1; off >>= 1)
            partial += __shfl_xor(partial, off, 64);
        if (lane == 0) {
            eRange[0] = partial;
            eRange[1] = partial + tot[bk];
        }
    }

    // ---- A slot ownership: 512 slots (128 rows x 4 kg), 1 per thread
    const int arow = tid >> 2, akg = tid & 3;
    const int aslot = (akg ^ ((arow >> 1) & 3)) * 8;   // swizzled ushort offset

    float4 areg[3][2];   // [buf][half]

#define G1_ISSUE(cc, bb)                                                     \
    {                                                                        \
        int g0 = row0 + arow;                                                \
        areg[bb][0] = make_float4(0.f, 0.f, 0.f, 0.f);                       \
        areg[bb][1] = make_float4(0.f, 0.f, 0.f, 0.f);                       \
        if (g0 < nRows) {                                                    \
            const float* p = &A[(size_t)g0 * 256 + (cc) * 32 + akg * 8];     \
            areg[bb][0] = *(const float4*)p;                                 \
            areg[bb][1] = *(const float4*)(p + 4);                           \
        }                                                                    \
    }

    G1_ISSUE(0, 0)
    G1_ISSUE(1, 1)
    G1_ISSUE(2, 2)
    __syncthreads();   // eRange + hist-zero visible

    // ---- degree histogram for rows [row0, row0+128) from sorted keys
    {
        int e0 = eRange[0], e1 = eRange[1];
        for (int e = e0 + tid; e < e1; e += 512) {
            int s = ss[e];
            if ((s >> 7) == blockIdx.x)
                atomicAdd(&hist[s & 127], 1);       // LDS atomic
        }
    }

    f32x4 acc[8];
#pragma unroll
    for (int t = 0; t < 8; ++t) acc[t] = (f32x4){0.f, 0.f, 0.f, 0.f};

#pragma unroll
    for (int c = 0; c < 8; ++c) {
        if (c > 0) __syncthreads();          // prior compute done with As
        const int buf = c % 3;
        // convert + write chunk c into As
        {
            float4 v0 = areg[buf][0], v1 = areg[buf][1];
            ushort u[8];
            u[0] = f2bf(v0.x); u[1] = f2bf(v0.y); u[2] = f2bf(v0.z); u[3] = f2bf(v0.w);
            u[4] = f2bf(v1.x); u[5] = f2bf(v1.y); u[6] = f2bf(v1.z); u[7] = f2bf(v1.w);
            *(short8*)&As[arow * 32 + aslot] = *(const short8*)u;
        }
        if (c + 3 < 8) G1_ISSUE(c + 3, buf)  // refill consumed buffer
        __syncthreads();
        // compute: one K-step of 32
        {
            int ra0 = wm * 32 + r, ra1 = wm * 32 + 16 + r;
            short8 a0 = *(const short8*)&As[ra0 * 32 + ((q ^ ((ra0 >> 1) & 3)) * 8)];
            short8 a1 = *(const short8*)&As[ra1 * 32 + ((q ^ ((ra1 >> 1) & 3)) * 8)];
            int sB = c * 4 + q;
#pragma unroll
            for (int t = 0; t < 4; ++t) {
                int col = wn * 64 + t * 16 + r;
                short8 b = *(const short8*)&Bs[col * 256 + ((sB ^ (col & 7)) * 8)];
                acc[t]     = __builtin_amdgcn_mfma_f32_16x16x32_bf16(a0, b, acc[t], 0, 0, 0);
                acc[4 + t] = __builtin_amdgcn_mfma_f32_16x16x32_bf16(a1, b, acc[4 + t], 0, 0, 0);
            }
        }
    }
#undef G1_ISSUE

    // epilogue: apply src-side normalization (from fused histogram), bf16 h1
#pragma unroll
    for (int fr = 0; fr < 2; ++fr)
#pragma unroll
        for (int t = 0; t < 4; ++t) {
            int col = wn * 64 + t * 16 + r;
#pragma unroll
            for (int reg = 0; reg < 4; ++reg) {
                int lr = wm * 32 + fr * 16 + q * 4 + reg;
                int g = row0 + lr;
                if (g < nRows) {
                    float sc = rsqrtf((float)max(hist[lr], 1));
                    C[(size_t)g * 128 + col] = f2bf(acc[fr * 4 + t][reg] * sc);
                }
            }
        }
}

// ---------------------------------------------------------------------------
// CSR gather over pre-scaled h1: pure sum, one wave per node (high TLP).
// Main loop: 4 edges in flight per lane (16/node); tail: one predicated
// 3-deep batch (clamped indices, masked accumulate) instead of serial singles.
static __device__ __forceinline__ void acc8(float* a, uint4 u) {
    union { unsigned int i; float f; } c;
    c.i = u.x << 16;          a[0] += c.f;
    c.i = u.x & 0xffff0000u;  a[1] += c.f;
    c.i = u.y << 16;          a[2] += c.f;
    c.i = u.y & 0xffff0000u;  a[3] += c.f;
    c.i = u.z << 16;          a[4] += c.f;
    c.i = u.z & 0xffff0000u;  a[5] += c.f;
    c.i = u.w << 16;          a[6] += c.f;
    c.i = u.w & 0xffff0000u;  a[7] += c.f;
}

__global__ __launch_bounds__(256) void gather_kernel(
    const ushort* __restrict__ h1, const int* __restrict__ src,
    const int* __restrict__ rp, const float* __restrict__ b_conv,
    ushort* __restrict__ h2, int N)
{
    int n = (blockIdx.x * 256 + threadIdx.x) >> 6;
    int lane = threadIdx.x & 63;
    if (n >= N) return;
    const int g = lane >> 4;
    const int c = lane & 15;
    int e0 = rp[n], e1 = rp[n + 1];

    float a[8];
#pragma unroll
    for (int j = 0; j < 8; ++j) a[j] = 0.f;

    int e = e0 + g;
    for (; e + 12 < e1; e += 16) {         // 4 edges in flight per lane
        int s0 = src[e], s1 = src[e + 4], s2 = src[e + 8], s3 = src[e + 12];
        uint4 u0 = *(const uint4*)&h1[((size_t)(unsigned)s0 << 7) + c * 8];
        uint4 u1 = *(const uint4*)&h1[((size_t)(unsigned)s1 << 7) + c * 8];
        uint4 u2 = *(const uint4*)&h1[((size_t)(unsigned)s2 << 7) + c * 8];
        uint4 u3 = *(const uint4*)&h1[((size_t)(unsigned)s3 << 7) + c * 8];
        acc8(a, u0); acc8(a, u1); acc8(a, u2); acc8(a, u3);
    }
    if (e < e1) {                          // predicated 3-deep tail
        int sA = src[e];
        int sB = (e + 4 < e1) ? src[e + 4] : sA;
        int sC = (e + 8 < e1) ? src[e + 8] : sA;
        uint4 uA = *(const uint4*)&h1[((size_t)(unsigned)sA << 7) + c * 8];
        uint4 uB = *(const uint4*)&h1[((size_t)(unsigned)sB << 7) + c * 8];
        uint4 uC = *(const uint4*)&h1[((size_t)(unsigned)sC << 7) + c * 8];
        acc8(a, uA);
        if (e + 4 < e1) acc8(a, uB);
        if (e + 8 < e1) acc8(a, uC);
    }

#pragma unroll
    for (int j = 0; j < 8; ++j) {
        a[j] += __shfl_xor(a[j], 16, 64);
        a[j] += __shfl_xor(a[j], 32, 64);
    }

    if (g == 0) {
        float sc = rsqrtf((float)max(e1 - e0, 1));
        ushort o[8];
#pragma unroll
        for (int j = 0; j < 8; ++j)
            o[j] = f2bf(fmaxf(fmaf(a[j], sc, b_conv[c * 8 + j]), 0.f));
        *(short8*)&h2[((size_t)(unsigned)n << 7) + c * 8] = *(const short8*)o;
    }
}

// ---------------------------------------------------------------------------
// GEMM2+GEMM3: 128 rows per block, 512 threads, 64 KB LDS total.
// AsTs (32 KB) holds the h2 tile, then T. Ws (32 KB) is a weight window:
// W1 for stage1, then W2 in two 128-col halves for stage2 (restaged from L2).
// Output stored with non-temporal hints (out is never re-read).
__global__ __launch_bounds__(512) void gemm23_kernel(
    const ushort* __restrict__ A, const ushort* __restrict__ W1b,
    const ushort* __restrict__ W2b, const float* __restrict__ b1,
    const float* __restrict__ b2, float* __restrict__ out, int nRows)
{
    __shared__ ushort AsTs[128 * 128];  // 32 KB: h2 tile, then T tile
    __shared__ ushort Ws[128 * 128];    // 32 KB: W1, then W2 half-windows

    const int tid  = threadIdx.x;
    const int lane = tid & 63;
    const int w    = tid >> 6;
    const int wm   = w >> 1;
    const int wn   = w & 1;
    const int r    = lane & 15;
    const int q    = lane >> 4;
    const int row0 = blockIdx.x * 128;

    // ---- stage h2 tile (guarded) + W1, swizzled
#pragma unroll
    for (int s = 0; s < 4; ++s) {
        int idx = s * 512 + tid;
        int row = idx >> 4, kg = idx & 15;
        int g = row0 + row;
        short8 v = (short8){0, 0, 0, 0, 0, 0, 0, 0};
        if (g < nRows) v = *(const short8*)&A[(size_t)g * 128 + kg * 8];
        *(short8*)&AsTs[row * 128 + ((kg ^ (row & 7)) * 8)] = v;
    }
#pragma unroll
    for (int s = 0; s < 4; ++s) {
        int idx = s * 512 + tid;
        int col = idx >> 4, kg = idx & 15;
        *(short8*)&Ws[col * 128 + ((kg ^ (col & 7)) * 8)] =
            *(const short8*)&W1b[(size_t)col * 128 + kg * 8];
    }
    __syncthreads();

    // ---- stage1: acc1 = h2 @ W1^T  (K=128)
    f32x4 acc1[8];
#pragma unroll
    for (int t = 0; t < 8; ++t) acc1[t] = (f32x4){0.f, 0.f, 0.f, 0.f};
#pragma unroll
    for (int ks = 0; ks < 4; ++ks) {
        int sA = ks * 4 + q;
        int ra0 = wm * 32 + r, ra1 = wm * 32 + 16 + r;
        short8 a0 = *(const short8*)&AsTs[ra0 * 128 + ((sA ^ (ra0 & 7)) * 8)];
        short8 a1 = *(const short8*)&AsTs[ra1 * 128 + ((sA ^ (ra1 & 7)) * 8)];
#pragma unroll
        for (int t = 0; t < 4; ++t) {
            int col = wn * 64 + t * 16 + r;
            short8 b = *(const short8*)&Ws[col * 128 + ((sA ^ (col & 7)) * 8)];
            acc1[t]     = __builtin_amdgcn_mfma_f32_16x16x32_bf16(a0, b, acc1[t], 0, 0, 0);
            acc1[4 + t] = __builtin_amdgcn_mfma_f32_16x16x32_bf16(a1, b, acc1[4 + t], 0, 0, 0);
        }
    }
    __syncthreads();   // AsTs + Ws reads done -> safe to overwrite both

    // ---- T = relu(acc1 + b1) -> AsTs; stage W2 cols 0..127 -> Ws
#pragma unroll
    for (int fr = 0; fr < 2; ++fr)
#pragma unroll
        for (int t = 0; t < 4; ++t) {
            int col = wn * 64 + t * 16 + r;
            float bo = b1[col];
#pragma unroll
            for (int reg = 0; reg < 4; ++reg) {
                int row = wm * 32 + fr * 16 + q * 4 + reg;
                float v = fmaxf(acc1[fr * 4 + t][reg] + bo, 0.f);
                AsTs[row * 128 + (((col >> 3) ^ (row & 7)) * 8) + (col & 7)] = f2bf(v);
            }
        }
#pragma unroll
    for (int s = 0; s < 4; ++s) {
        int idx = s * 512 + tid;
        int col = idx >> 4, kg = idx & 15;
        *(short8*)&Ws[col * 128 + ((kg ^ (col & 7)) * 8)] =
            *(const short8*)&W2b[(size_t)col * 128 + kg * 8];
    }
    __syncthreads();

    // ---- stage2 half 0: cols 0..127 of out
    f32x4 acc2[16];
#pragma unroll
    for (int t = 0; t < 16; ++t) acc2[t] = (f32x4){0.f, 0.f, 0.f, 0.f};
#pragma unroll
    for (int ks = 0; ks < 4; ++ks) {
        int sA = ks * 4 + q;
        int ra0 = wm * 32 + r, ra1 = wm * 32 + 16 + r;
        short8 a0 = *(const short8*)&AsTs[ra0 * 128 + ((sA ^ (ra0 & 7)) * 8)];
        short8 a1 = *(const short8*)&AsTs[ra1 * 128 + ((sA ^ (ra1 & 7)) * 8)];
#pragma unroll
        for (int t = 0; t < 4; ++t) {
            int col = wn * 64 + t * 16 + r;
            short8 b = *(const short8*)&Ws[col * 128 + ((sA ^ (col & 7)) * 8)];
            acc2[t]     = __builtin_amdgcn_mfma_f32_16x16x32_bf16(a0, b, acc2[t], 0, 0, 0);
            acc2[4 + t] = __builtin_amdgcn_mfma_f32_16x16x32_bf16(a1, b, acc2[4 + t], 0, 0, 0);
        }
    }
    __syncthreads();   // Ws reads done

    // ---- restage Ws <- W2 cols 128..255
#pragma unroll
    for (int s = 0; s < 4; ++s) {
        int idx = s * 512 + tid;
        int col = idx >> 4, kg = idx & 15;
        *(short8*)&Ws[col * 128 + ((kg ^ (col & 7)) * 8)] =
            *(const short8*)&W2b[(size_t)(128 + col) * 128 + kg * 8];
    }
    __syncthreads();

    // ---- stage2 half 1: cols 128..255 of out
#pragma unroll
    for (int ks = 0; ks < 4; ++ks) {
        int sA = ks * 4 + q;
        int ra0 = wm * 32 + r, ra1 = wm * 32 + 16 + r;
        short8 a0 = *(const short8*)&AsTs[ra0 * 128 + ((sA ^ (ra0 & 7)) * 8)];
        short8 a1 = *(const short8*)&AsTs[ra1 * 128 + ((sA ^ (ra1 & 7)) * 8)];
#pragma unroll
        for (int t = 0; t < 4; ++t) {
            int col = wn * 64 + t * 16 + r;
            short8 b = *(const short8*)&Ws[col * 128 + ((sA ^ (col & 7)) * 8)];
            acc2[8 + t]  = __builtin_amdgcn_mfma_f32_16x16x32_bf16(a0, b, acc2[8 + t], 0, 0, 0);
            acc2[12 + t] = __builtin_amdgcn_mfma_f32_16x16x32_bf16(a1, b, acc2[12 + t], 0, 0, 0);
        }
    }

    // ---- epilogue: f32 out + b2 (both halves), non-temporal stores
#pragma unroll
    for (int h = 0; h < 2; ++h)
#pragma unroll
        for (int fr = 0; fr < 2; ++fr)
#pragma unroll
            for (int t = 0; t < 4; ++t) {
                int col = h * 128 + wn * 64 + t * 16 + r;
                float bo = b2[col];
#pragma unroll
                for (int reg = 0; reg < 4; ++reg) {
                    int g = row0 + wm * 32 + fr * 16 + q * 4 + reg;
                    if (g < nRows)
                        __builtin_nontemporal_store(
                            acc2[h * 8 + fr * 4 + t][reg] + bo,
                            &out[(size_t)g * 256 + col]);
                }
            }
}

// ---------------------------------------------------------------------------
extern "C" void kernel_launch(void* const* d_in, const int* in_sizes, int n_in,
                              void* d_out, int out_size, void* d_ws, size_t ws_size,
                              hipStream_t stream)
{
    const float* x      = (const float*)d_in[0];
    const int*   src    = (const int*)d_in[1];
    const int*   dst    = (const int*)d_in[2];
    const float* W_conv = (const float*)d_in[3];
    const float* b_conv = (const float*)d_in[4];
    const float* W1     = (const float*)d_in[5];
    const float* b1     = (const float*)d_in[6];
    const float* W2     = (const float*)d_in[7];
    const float* b2     = (const float*)d_in[8];
    float* out = (float*)d_out;

    const int N  = in_sizes[0] / 256;   // 100000
    const int nE = in_sizes[1];         // 1600000

    const int nBuk    = (N + 255) >> 8;                 // 391
    const int chunkSz = (nE + NCHUNK - 1) / NCHUNK;     // 6250

    // ws layout (ushort units for bf16 region, then ints):
    // h1 [N*128] | h2 [N*128] | WcT [128*256] | W1b [128*128] | W2b [256*128]
    // | rp [N+1] | tot [nBuk] | M [nBuk*NCHUNK] | ss [nE]
    ushort* h1  = (ushort*)d_ws;
    ushort* h2  = h1 + (size_t)N * 128;
    ushort* WcT = h2 + (size_t)N * 128;
    ushort* W1b = WcT + 128 * 256;
    ushort* W2b = W1b + 128 * 128;
    int* rp     = (int*)(W2b + 256 * 128);
    int* tot    = rp + (N + 1);
    int* M      = tot + nBuk;
    int* ss     = M + nBuk * NCHUNK;

    // ---- fused prep: weight convert + bucket hist + rowptr
    const int rowptrBlocks = (nE + 255) / 256;
    prep_kernel<<<WPREP_BLOCKS + NCHUNK + rowptrBlocks, 256, 0, stream>>>(
        W_conv, W1, W2, WcT, W1b, W2b, src, M, dst, rp, nE, N, nBuk, chunkSz);

    // ---- atomic-free bucket sort of src keys ----
    scanA_kernel<<<nBuk, 256, 0, stream>>>(M, tot);
    scatter_keys_kernel<<<NCHUNK, 256, 0, stream>>>(src, M, tot, ss, nE, nBuk, chunkSz);

    const int nBlocks128 = (N + 127) / 128;   // 782
    // h1 = bf16[rsqrt(outdeg) * (x @ W_conv)]  (count fused from ss)
    gemm1_kernel<<<nBlocks128, 512, 0, stream>>>(x, WcT, ss, tot, h1, N, nBuk);

    // h2 = bf16[relu(csr_sum(h1) * rsqrt(indeg) + b_conv)]  (high-TLP)
    gather_kernel<<<(N * 64 + 255) / 256, 256, 0, stream>>>(
        h1, src, rp, b_conv, h2, N);

    // out = relu(h2 @ W1^T + b1) @ W2^T + b2
    gemm23_kernel<<<nBlocks128, 512, 0, stream>>>(h2, W1b, W2b, b1, b2, out, N);
}